// Round 19
// baseline (79.271 us; speedup 1.0000x reference)
//
#include <hip/hip_runtime.h>
#include <hip/hip_bf16.h>
#include <cstdint>

// Problem constants
#define B_  128
#define F_  512
#define T_  60
#define C_  15
#define H1_ 128
#define H2_ 64

typedef short short8_t __attribute__((ext_vector_type(8)));   // 8 bf16 (4 VGPR)
typedef float f32x4    __attribute__((ext_vector_type(4)));   // MFMA acc

static __device__ __forceinline__ unsigned short f2bf(float f) {
    union { float f; uint32_t u; } v; v.f = f;
    uint32_t r = v.u + 0x7FFF + ((v.u >> 16) & 1);   // RNE
    return (unsigned short)(r >> 16);
}

// async 16B global -> LDS DMA (dest = wave-uniform base + lane*16)
static __device__ __forceinline__ void async_cp16(const unsigned short* g, unsigned short* l) {
    __builtin_amdgcn_global_load_lds(
        (const __attribute__((address_space(1))) unsigned int*)g,
        (__attribute__((address_space(3))) unsigned int*)l, 16, 0, 0);
}

// ---------------------------------------------------------------------------
// prep_all: ONE launch for all prep (R16-format images, BK=64 kc-chunks).
//   blocks 0..511   : repack_x  -> xTs (B, 8 kc, swizzled 64x64 image) bf16
//   blocks 512..631 : repack_w2 -> W2f fragment-major (16 frag x 512)
//   block  632      : camera sort + CHUNK TABLE (same-camera sample pairs)
//   blocks 633..1592: repack_w1 -> W1s (c,pq): 8 kc x swizzled 128x64 image
// ---------------------------------------------------------------------------
__global__ __launch_bounds__(256) void prep_all(
    const float* __restrict__ x, const float* __restrict__ W2,
    const float* __restrict__ W1, const int* __restrict__ cam,
    unsigned short* __restrict__ xTs, unsigned short* __restrict__ W2f,
    unsigned short* __restrict__ W1s, int* __restrict__ chunks,
    int* __restrict__ nchp)
{
    __shared__ float sm[12288];   // 48 KB
    const int blk = blockIdx.x, tid = threadIdx.x;

    if (blk < 512) {
        // ---------------- repack_x ----------------
        float (*xs)[61] = (float(*)[61])sm;          // 128 x 61 floats
        const int f0 = (blk & 3) * 128, b = blk >> 2;
        #pragma unroll
        for (int it = 0; it < 32; ++it) {
            int idx = tid + it * 256;                // 128*64
            int fl = idx >> 6, t = idx & 63;
            if (t < T_) xs[fl][t] = x[((size_t)b * F_ + f0 + fl) * T_ + t];
        }
        __syncthreads();
        #pragma unroll
        for (int it = 0; it < 8; ++it) {
            int idx = tid + it * 256;                // 64 t x 32 f-groups
            int t = idx >> 5, f4 = (idx & 31) * 4;
            ushort4 o;
            o.x = (t < T_) ? f2bf(xs[f4 + 0][t]) : 0;
            o.y = (t < T_) ? f2bf(xs[f4 + 1][t]) : 0;
            o.z = (t < T_) ? f2bf(xs[f4 + 2][t]) : 0;
            o.w = (t < T_) ? f2bf(xs[f4 + 3][t]) : 0;
            const int f = f0 + f4;
            const int kc = f >> 6, within = f & 63;
            const int cc = (within >> 3) ^ (t & 7), half = (within >> 2) & 1;
            *(ushort4*)(xTs + (size_t)b * 32768 + kc * 4096 + t * 64 + cc * 8 + half * 4) = o;
        }
    } else if (blk < 632) {
        // ---------------- repack_w2 (fragment-major) ------------------------
        float (*ls)[384] = (float(*)[384])sm;        // 32 x 384 floats (48KB)
        const int id = blk - 512;                    // 0..119
        const int i0 = (id & 3) * 32, o0 = ((id >> 2) & 1) * 32, c = id >> 3;
        #pragma unroll
        for (int it = 0; it < 12; ++it) {
            int idx = tid + it * 256;
            int il = idx / 96, r = idx - il * 96;
            float4 v = *(const float4*)(W2 + ((size_t)(c * H1_ + i0 + il)) * (H2_ * 12)
                                           + (size_t)o0 * 12 + r * 4);
            *(float4*)&ls[il][r * 4] = v;
        }
        __syncthreads();
        const int o_l = tid >> 3, i_l = (tid & 7) * 4;
        const int o  = o0 + o_l;
        const int nt = o >> 4, l15 = o & 15;
        const int lane = l15 + 16 * ((i_l >> 3) & 3);
        const int kk  = i0 >> 5;
        const int pos = i_l & 7;
        #pragma unroll
        for (int rs = 0; rs < 12; ++rs) {
            ushort4 v;
            v.x = f2bf(ls[i_l + 0][o_l * 12 + rs]);
            v.y = f2bf(ls[i_l + 1][o_l * 12 + rs]);
            v.z = f2bf(ls[i_l + 2][o_l * 12 + rs]);
            v.w = f2bf(ls[i_l + 3][o_l * 12 + rs]);
            *(ushort4*)(W2f + ((size_t)(c * 12 + rs) * 16 + nt * 4 + kk) * 512
                            + lane * 8 + pos) = v;
        }
    } else if (blk == 632) {
        // ---------------- camera sort + chunk table ----------------
        int* cs  = (int*)sm;         // [128] camera per sample
        int* ods = cs + 128;         // [128] sorted order
        if (tid < B_) cs[tid] = cam[tid];
        __syncthreads();
        if (tid < B_) {
            const int cb = cs[tid];
            int rank = 0;
            #pragma unroll 16
            for (int j = 0; j < B_; ++j) {
                int cj = cs[j];
                rank += (cj < cb || (cj == cb && j < tid)) ? 1 : 0;
            }
            ods[rank] = tid;
        }
        __syncthreads();
        if (tid == 0) {
            int k = 0, j = 0;
            while (j < B_) {
                int b0 = ods[j], bn;
                if (j + 1 < B_ && cs[ods[j + 1]] == cs[b0]) { bn = ods[j + 1]; j += 2; }
                else { bn = b0; j += 1; }       // odd tail: duplicate (benign)
                chunks[2 * k]     = b0;
                chunks[2 * k + 1] = bn;
                ++k;
            }
            nchp[0] = k;                        // <= 71
        }
    } else {
        // ---------------- repack_w1 ----------------
        float (*ls)[384] = (float(*)[384])sm;        // 32 x 384
        const int id = blk - 633;                    // 0..959
        const int f0 = (id & 15) * 32, i0 = ((id >> 4) & 3) * 32, c = id >> 6;
        #pragma unroll
        for (int it = 0; it < 12; ++it) {
            int idx = tid + it * 256;                // 3072 float4
            int fl = idx / 96, r = idx - fl * 96;
            float4 v = *(const float4*)(W1 + ((size_t)(c * F_ + f0 + fl)) * (H1_ * 12)
                                           + (size_t)i0 * 12 + r * 4);
            *(float4*)&ls[fl][r * 4] = v;
        }
        __syncthreads();
        const int i_l = tid >> 3, f_l = (tid & 7) * 4;
        const int i = i0 + i_l, f = f0 + f_l;
        const int kc = f >> 6, within = f & 63;
        const int cc = (within >> 3) ^ (i & 7), half = (within >> 2) & 1;
        #pragma unroll
        for (int pq = 0; pq < 12; ++pq) {
            ushort4 o;
            o.x = f2bf(ls[f_l + 0][i_l * 12 + pq]);
            o.y = f2bf(ls[f_l + 1][i_l * 12 + pq]);
            o.z = f2bf(ls[f_l + 2][i_l * 12 + pq]);
            o.w = f2bf(ls[f_l + 3][i_l * 12 + pq]);
            *(ushort4*)(W1s + (size_t)(c * 12 + pq) * 65536
                            + kc * 8192 + i * 64 + cc * 8 + half * 4) = o;
        }
    }
}

// ---------------------------------------------------------------------------
// Fused decoder v19: SAME-CAMERA SAMPLE PAIRING (M=128 grouped GEMM).
// Block = (chunk, pq); chunk = 2 camera-sorted samples sharing one W1 slice.
// Per K-step the B-tile feeds 2x the MFMA (32/wave vs 16) and W1's L2 read
// traffic halves. LDS: 2 bufs x (A0 4096 | A1 4096 | B 8192) ush = 64 KB.
// Counted vmcnt(8) (8 staging ops/wave/step), raw barriers (R16 pattern).
// h1 for sample0/1 lands in buf0/buf1 regions; phase 2 loops samples
// sequentially (VGPR flat), swapped mfma + cheap g-reduction epilogue.
// ---------------------------------------------------------------------------
__global__ __launch_bounds__(256) void fused_all(
    const unsigned short* __restrict__ xTs, const unsigned short* __restrict__ W1s,
    const unsigned short* __restrict__ W2f, const int* __restrict__ cam,
    const int* __restrict__ chunks, const int* __restrict__ nchp,
    const float* __restrict__ b1, const float* __restrict__ b2,
    const float* __restrict__ W3, const float* __restrict__ b3,
    float* __restrict__ out)
{
    __shared__ __align__(16) unsigned short smem[32768];   // 64 KB

    const int idx = blockIdx.x;
    const int swz = (idx & 7) * 108 + (idx >> 3);   // bijective (864 = 8*108)
    const int chunk = swz / 12, pq = swz - chunk * 12;
    if (chunk >= nchp[0]) return;
    const int bA = chunks[2 * chunk], bB = chunks[2 * chunk + 1];

    const int tid = threadIdx.x;
    const int w = tid >> 6, l = tid & 63;
    const int l15 = l & 15, g = l >> 4;
    const int c = cam[bA];

    // ---------------- Phase 1: h1(128x128) = [xA;xB](128x512) * W1^T --------
    const unsigned short* xcA = xTs + (size_t)bA * 32768;               // 8 x 4096
    const unsigned short* xcB = xTs + (size_t)bB * 32768;               // 8 x 4096
    const unsigned short* wchunk = W1s + (size_t)(c * 12 + pq) * 65536; // 8 x 8192

    // per-wave stage: 2 A0 + 2 A1 + 4 B = 8 cp16 ops
    #define STAGE1(kc, buf)                                                       \
        {                                                                         \
            _Pragma("unroll")                                                     \
            for (int k = 0; k < 2; ++k)                                           \
                async_cp16(xcA + (kc) * 4096 + (w * 2 + k) * 512 + l * 8,         \
                           smem + (buf) * 16384 + (w * 2 + k) * 512 + l * 8);     \
            _Pragma("unroll")                                                     \
            for (int k = 0; k < 2; ++k)                                           \
                async_cp16(xcB + (kc) * 4096 + (w * 2 + k) * 512 + l * 8,         \
                           smem + (buf) * 16384 + 4096 + (w * 2 + k) * 512 + l * 8); \
            _Pragma("unroll")                                                     \
            for (int k = 0; k < 4; ++k)                                           \
                async_cp16(wchunk + (kc) * 8192 + (w * 4 + k) * 512 + l * 8,      \
                           smem + (buf) * 16384 + 8192 + (w * 4 + k) * 512 + l * 8); \
        }

    f32x4 acc1[8][2];
    #pragma unroll
    for (int mt = 0; mt < 8; ++mt) {
        acc1[mt][0] = (f32x4){0.f, 0.f, 0.f, 0.f};
        acc1[mt][1] = (f32x4){0.f, 0.f, 0.f, 0.f};
    }

    STAGE1(0, 0);
    STAGE1(1, 1);

    const int sxor = (l15 & 7);
    #pragma unroll
    for (int kc = 0; kc < 8; ++kc) {
        if (kc < 7) { asm volatile("s_waitcnt vmcnt(8)" ::: "memory"); }
        else        { asm volatile("s_waitcnt vmcnt(0)" ::: "memory"); }
        __builtin_amdgcn_s_barrier();
        asm volatile("" ::: "memory");   // pin ds_reads below the barrier

        const int base = (kc & 1) * 16384;
        #pragma unroll
        for (int kk2 = 0; kk2 < 2; ++kk2) {
            const int cc = (kk2 * 4 + g) ^ sxor;
            short8_t af[8], bf[2];
            #pragma unroll
            for (int mt = 0; mt < 4; ++mt)
                af[mt] = *(const short8_t*)(smem + base + (16 * mt + l15) * 64 + cc * 8);
            #pragma unroll
            for (int mt = 0; mt < 4; ++mt)
                af[4 + mt] = *(const short8_t*)(smem + base + 4096
                                                + (16 * mt + l15) * 64 + cc * 8);
            #pragma unroll
            for (int ni = 0; ni < 2; ++ni)
                bf[ni] = *(const short8_t*)(smem + base + 8192
                                            + (32 * w + 16 * ni + l15) * 64 + cc * 8);
            #pragma unroll
            for (int mt = 0; mt < 8; ++mt)
                #pragma unroll
                for (int ni = 0; ni < 2; ++ni)
                    acc1[mt][ni] = __builtin_amdgcn_mfma_f32_16x16x32_bf16(
                        af[mt], bf[ni], acc1[mt][ni], 0, 0, 0);
        }

        asm volatile("" ::: "memory");
        __builtin_amdgcn_s_barrier();    // all waves done with buf[kc&1]
        if (kc < 6) STAGE1(kc + 2, kc & 1);
    }
    #undef STAGE1

    // ---- phase-2 prefetches issued before the h1s barrier (T14) ----
    const unsigned short* W2base = W2f + (size_t)(c * 12 + w * 3) * 8192;
    short8_t bfr[2][4];
    #pragma unroll
    for (int kk = 0; kk < 4; ++kk)
        bfr[0][kk] = *(const short8_t*)(W2base + kk * 512 + l * 8);   // smp0 seg0

    float w3v[4][4], b2v[4][4];
    #pragma unroll
    for (int nt = 0; nt < 4; ++nt)
        #pragma unroll
        for (int r = 0; r < 4; ++r) {
            w3v[nt][r] = W3[c * H2_ + nt * 16 + g * 4 + r];
            b2v[nt][r] = b2[c * H2_ + nt * 16 + g * 4 + r];
        }
    const float b3v = b3[c];
    const int p = pq >> 2, q = pq & 3;

    // bias + relu -> h1s: sample0 in buf0 region, sample1 in buf1 region
    // ([64][136] each; writes safe: both bufs fully consumed + barriered)
    #pragma unroll
    for (int ni = 0; ni < 2; ++ni) {
        const int i = 32 * w + 16 * ni + l15;
        const float b1v = b1[c * H1_ + i];
        #pragma unroll
        for (int mt = 0; mt < 8; ++mt) {
            unsigned short* h1s = smem + (mt >> 2) * 16384;
            const int mtl = mt & 3;
            #pragma unroll
            for (int r = 0; r < 4; ++r) {
                float h = acc1[mt][ni][r] + b1v;
                h = h > 0.f ? h : 0.f;
                h1s[(16 * mtl + 4 * g + r) * 136 + i] = f2bf(h);
            }
        }
    }
    __syncthreads();

    // ---------------- Phase 2 (swapped operands), per sample ----------------
    #pragma unroll
    for (int smp = 0; smp < 2; ++smp) {
        const unsigned short* h1s = smem + smp * 16384;
        const int bb = smp ? bB : bA;

        short8_t a2[4][4];
        #pragma unroll
        for (int mt = 0; mt < 4; ++mt)
            #pragma unroll
            for (int kk = 0; kk < 4; ++kk)
                a2[mt][kk] = *(const short8_t*)&h1s[(16 * mt + l15) * 136 + 32 * kk + 8 * g];

        if (smp == 1) {
            #pragma unroll
            for (int kk = 0; kk < 4; ++kk)
                bfr[0][kk] = *(const short8_t*)(W2base + kk * 512 + l * 8);
        }

        float s[4] = {0.f, 0.f, 0.f, 0.f};

        // seg = 0..11 : rs_local = seg>>2, nt = seg&3 ; 1-ahead 2-slot prefetch
        #pragma unroll
        for (int seg = 0; seg < 12; ++seg) {
            if (seg < 11) {
                const int ns = seg + 1;
                const unsigned short* nb = W2base + (ns >> 2) * 8192 + ((ns & 3) * 4) * 512;
                #pragma unroll
                for (int kk = 0; kk < 4; ++kk)
                    bfr[(seg + 1) & 1][kk] = *(const short8_t*)(nb + kk * 512 + l * 8);
            }
            const int nt = seg & 3;
            #pragma unroll
            for (int mt = 0; mt < 4; ++mt) {
                f32x4 acc2 = (f32x4){0.f, 0.f, 0.f, 0.f};
                #pragma unroll
                for (int kk = 0; kk < 4; ++kk)
                    acc2 = __builtin_amdgcn_mfma_f32_16x16x32_bf16(
                        bfr[seg & 1][kk], a2[mt][kk], acc2, 0, 0, 0);
                #pragma unroll
                for (int r = 0; r < 4; ++r)
                    s[mt] = fmaf(w3v[nt][r], fmaxf(acc2[r] + b2v[nt][r], 0.f), s[mt]);
            }

            if (nt == 3) {
                const int rs = w * 3 + (seg >> 2);
                const int hrow = p * 3 + (rs >> 2), wcol = q * 4 + (rs & 3);
                #pragma unroll
                for (int mt = 0; mt < 4; ++mt) {
                    s[mt] += __shfl_xor(s[mt], 16);
                    s[mt] += __shfl_xor(s[mt], 32);
                }
                float v = (g & 1) ? ((g & 2) ? s[3] : s[1]) : ((g & 2) ? s[2] : s[0]);
                v += b3v;
                if (l < T_)
                    out[(((size_t)bb * T_ + l) * 9 + hrow) * 16 + wcol] =
                        1.f / (1.f + __expf(-v));
                s[0] = s[1] = s[2] = s[3] = 0.f;
            }
        }
    }
}

// ---------------------------------------------------------------------------
// fp32 VALU fallback — used only if ws too small
// ---------------------------------------------------------------------------
__global__ __launch_bounds__(256) void fused_decoder_f32(
    const float* __restrict__ x,   const int* __restrict__ cam,
    const float* __restrict__ W1,  const float* __restrict__ b1,
    const float* __restrict__ W2,  const float* __restrict__ b2,
    const float* __restrict__ W3,  const float* __restrict__ b3,
    float* __restrict__ out)
{
    __shared__ float h1s[T_ * H1_];
    __shared__ float stage[8192];

    const int pq  = blockIdx.x;
    const int b   = blockIdx.y;
    const int p   = pq >> 2, q = pq & 3;
    const int tid = threadIdx.x;
    const int c   = cam[b];

    float* xs  = stage;
    float* w1s = stage + 2048;

    const int ig = tid & 31;
    const int tg = tid >> 5;

    float acc[8][4];
    #pragma unroll
    for (int a = 0; a < 8; ++a)
        #pragma unroll
        for (int j = 0; j < 4; ++j) acc[a][j] = 0.f;

    for (int f0 = 0; f0 < F_; f0 += 32) {
        __syncthreads();
        {
            int lane = tid & 63;
            int sub  = tid >> 6;
            if (lane < T_) {
                #pragma unroll
                for (int m = 0; m < 8; ++m) {
                    int kk = sub * 8 + m;
                    xs[kk * 64 + lane] = x[((size_t)b * F_ + f0 + kk) * T_ + lane];
                }
            }
        }
        for (int e = tid; e < 32 * H1_; e += 256) {
            int kk = e >> 7, i = e & 127;
            w1s[e] = W1[(((size_t)c * F_ + f0 + kk) * H1_ + i) * 12 + pq];
        }
        __syncthreads();
        #pragma unroll 8
        for (int kk = 0; kk < 32; ++kk) {
            float4 bv = *(const float4*)&w1s[kk * 128 + ig * 4];
            float4 a0 = *(const float4*)&xs[kk * 64 + tg * 8];
            float4 a1 = *(const float4*)&xs[kk * 64 + tg * 8 + 4];
            float at[8] = {a0.x, a0.y, a0.z, a0.w, a1.x, a1.y, a1.z, a1.w};
            #pragma unroll
            for (int tt = 0; tt < 8; ++tt) {
                acc[tt][0] = fmaf(at[tt], bv.x, acc[tt][0]);
                acc[tt][1] = fmaf(at[tt], bv.y, acc[tt][1]);
                acc[tt][2] = fmaf(at[tt], bv.z, acc[tt][2]);
                acc[tt][3] = fmaf(at[tt], bv.w, acc[tt][3]);
            }
        }
    }
    {
        float4 b1v = *(const float4*)&b1[c * H1_ + ig * 4];
        #pragma unroll
        for (int tt = 0; tt < 8; ++tt) {
            int t = tg * 8 + tt;
            if (t < T_) {
                float4 hv;
                hv.x = fmaxf(acc[tt][0] + b1v.x, 0.f);
                hv.y = fmaxf(acc[tt][1] + b1v.y, 0.f);
                hv.z = fmaxf(acc[tt][2] + b1v.z, 0.f);
                hv.w = fmaxf(acc[tt][3] + b1v.w, 0.f);
                *(float4*)&h1s[t * H1_ + ig * 4] = hv;
            }
        }
    }

    const int lane = tid & 63;
    const int wv   = tid >> 6;
    const float w3v = W3[c * H2_ + lane];
    const float b2v = b2[c * H2_ + lane];
    const float b3v = b3[c];
    float* w2s = stage;

    for (int rs = 0; rs < 12; ++rs) {
        __syncthreads();
        for (int e = tid; e < H1_ * H2_; e += 256) {
            int i = e >> 6, o = e & 63;
            w2s[e] = W2[(((size_t)c * H1_ + i) * H2_ + o) * 12 + rs];
        }
        __syncthreads();

        float acc2[15];
        #pragma unroll
        for (int j = 0; j < 15; ++j) acc2[j] = 0.f;

        for (int i = 0; i < H1_; i += 4) {
            float wa = w2s[(i + 0) * 64 + lane];
            float wb = w2s[(i + 1) * 64 + lane];
            float wc = w2s[(i + 2) * 64 + lane];
            float wd = w2s[(i + 3) * 64 + lane];
            #pragma unroll
            for (int j = 0; j < 15; ++j) {
                float4 h = *(const float4*)&h1s[(wv * 15 + j) * H1_ + i];
                acc2[j] = fmaf(h.x, wa, acc2[j]);
                acc2[j] = fmaf(h.y, wb, acc2[j]);
                acc2[j] = fmaf(h.z, wc, acc2[j]);
                acc2[j] = fmaf(h.w, wd, acc2[j]);
            }
        }

        const int r = rs >> 2, s = rs & 3;
        const int hrow = p * 3 + r, wcol = q * 4 + s;
        #pragma unroll
        for (int j = 0; j < 15; ++j) {
            float y = w3v * fmaxf(acc2[j] + b2v, 0.f);
            #pragma unroll
            for (int m = 32; m > 0; m >>= 1) y += __shfl_xor(y, m, 64);
            if (lane == j) {
                int t = wv * 15 + j;
                float v = y + b3v;
                out[(((size_t)b * T_ + t) * 9 + hrow) * 16 + wcol] = 1.f / (1.f + __expf(-v));
            }
        }
    }
}

// ---------------------------------------------------------------------------
extern "C" void kernel_launch(void* const* d_in, const int* in_sizes, int n_in,
                              void* d_out, int out_size, void* d_ws, size_t ws_size,
                              hipStream_t stream) {
    const float* x   = (const float*)d_in[0];
    const int*   cam = (const int*)  d_in[1];
    const float* W1  = (const float*)d_in[2];
    const float* b1  = (const float*)d_in[3];
    const float* W2  = (const float*)d_in[4];
    const float* b2  = (const float*)d_in[5];
    const float* W3  = (const float*)d_in[6];
    const float* b3  = (const float*)d_in[7];
    float* outp = (float*)d_out;

    const size_t n_xT  = (size_t)B_ * 32768;            //  4,194,304 (8 kc x 4096)
    const size_t n_w1s = (size_t)C_ * 12 * 65536;       // 11,796,480 (8 kc x 8192)
    const size_t n_w2f = (size_t)C_ * 12 * 16 * 512;    //  1,474,560 (fragment-major)
    const size_t needed = (n_xT + n_w1s + n_w2f) * sizeof(unsigned short)
                        + (144 + 1) * sizeof(int);

    if (d_ws != nullptr && ws_size >= needed) {
        unsigned short* xTs = (unsigned short*)d_ws;
        unsigned short* W1p = xTs + n_xT;
        unsigned short* W2p = W1p + n_w1s;
        int* chunks = (int*)(W2p + n_w2f);   // 72 x 2 ints
        int* nchp   = chunks + 144;
        prep_all<<<1593, 256, 0, stream>>>(x, W2, W1, cam, xTs, W2p, W1p, chunks, nchp);
        fused_all<<<dim3(864), 256, 0, stream>>>(
            xTs, W1p, W2p, cam, chunks, nchp, b1, b2, W3, b3, outp);
    } else {
        fused_decoder_f32<<<dim3(12, B_), 256, 0, stream>>>(
            x, cam, W1, b1, W2, b2, W3, b3, outp);
    }
}

// Round 20
// 60.586 us; speedup vs baseline: 1.3084x; 1.3084x over previous
//
#include <hip/hip_runtime.h>
#include <hip/hip_bf16.h>
#include <cstdint>

// Problem constants
#define B_  128
#define F_  512
#define T_  60
#define C_  15
#define H1_ 128
#define H2_ 64

typedef short short8_t __attribute__((ext_vector_type(8)));   // 8 bf16 (4 VGPR)
typedef float f32x4    __attribute__((ext_vector_type(4)));   // MFMA acc

static __device__ __forceinline__ unsigned short f2bf(float f) {
    union { float f; uint32_t u; } v; v.f = f;
    uint32_t r = v.u + 0x7FFF + ((v.u >> 16) & 1);   // RNE
    return (unsigned short)(r >> 16);
}

// async 16B global -> LDS DMA (dest = wave-uniform base + lane*16)
static __device__ __forceinline__ void async_cp16(const unsigned short* g, unsigned short* l) {
    __builtin_amdgcn_global_load_lds(
        (const __attribute__((address_space(1))) unsigned int*)g,
        (__attribute__((address_space(3))) unsigned int*)l, 16, 0, 0);
}

// ---------------------------------------------------------------------------
// prep_all: ONE launch for all prep (R16-format images, BK=64 kc-chunks).
//   blocks 0..511   : repack_x  -> xTs (B, 8 kc, swizzled 64x64 image) bf16
//                     unit (kc,t,cc): k = kc*64 + (cc ^ (t&7))*8 .. +8
//   blocks 512..631 : repack_w2 -> W2f fragment-major (16 frag x 512)
//   block  632      : make_order (camera sort)
//   blocks 633..1592: repack_w1 -> W1s (c,pq): 8 kc x swizzled 128x64 image
// ---------------------------------------------------------------------------
__global__ __launch_bounds__(256) void prep_all(
    const float* __restrict__ x, const float* __restrict__ W2,
    const float* __restrict__ W1, const int* __restrict__ cam,
    unsigned short* __restrict__ xTs, unsigned short* __restrict__ W2f,
    unsigned short* __restrict__ W1s, int* __restrict__ ord)
{
    __shared__ float sm[12288];   // 48 KB
    const int blk = blockIdx.x, tid = threadIdx.x;

    if (blk < 512) {
        // ---------------- repack_x ----------------
        float (*xs)[61] = (float(*)[61])sm;          // 128 x 61 floats
        const int f0 = (blk & 3) * 128, b = blk >> 2;
        #pragma unroll
        for (int it = 0; it < 32; ++it) {
            int idx = tid + it * 256;                // 128*64
            int fl = idx >> 6, t = idx & 63;
            if (t < T_) xs[fl][t] = x[((size_t)b * F_ + f0 + fl) * T_ + t];
        }
        __syncthreads();
        #pragma unroll
        for (int it = 0; it < 8; ++it) {
            int idx = tid + it * 256;                // 64 t x 32 f-groups
            int t = idx >> 5, f4 = (idx & 31) * 4;
            ushort4 o;
            o.x = (t < T_) ? f2bf(xs[f4 + 0][t]) : 0;
            o.y = (t < T_) ? f2bf(xs[f4 + 1][t]) : 0;
            o.z = (t < T_) ? f2bf(xs[f4 + 2][t]) : 0;
            o.w = (t < T_) ? f2bf(xs[f4 + 3][t]) : 0;
            const int f = f0 + f4;
            const int kc = f >> 6, within = f & 63;
            const int cc = (within >> 3) ^ (t & 7), half = (within >> 2) & 1;
            *(ushort4*)(xTs + (size_t)b * 32768 + kc * 4096 + t * 64 + cc * 8 + half * 4) = o;
        }
    } else if (blk < 632) {
        // ---------------- repack_w2 (fragment-major) ------------------------
        float (*ls)[384] = (float(*)[384])sm;        // 32 x 384 floats (48KB)
        const int id = blk - 512;                    // 0..119
        const int i0 = (id & 3) * 32, o0 = ((id >> 2) & 1) * 32, c = id >> 3;
        #pragma unroll
        for (int it = 0; it < 12; ++it) {
            int idx = tid + it * 256;
            int il = idx / 96, r = idx - il * 96;
            float4 v = *(const float4*)(W2 + ((size_t)(c * H1_ + i0 + il)) * (H2_ * 12)
                                           + (size_t)o0 * 12 + r * 4);
            *(float4*)&ls[il][r * 4] = v;
        }
        __syncthreads();
        const int o_l = tid >> 3, i_l = (tid & 7) * 4;
        const int o  = o0 + o_l;
        const int nt = o >> 4, l15 = o & 15;
        const int lane = l15 + 16 * ((i_l >> 3) & 3);
        const int kk  = i0 >> 5;
        const int pos = i_l & 7;
        #pragma unroll
        for (int rs = 0; rs < 12; ++rs) {
            ushort4 v;
            v.x = f2bf(ls[i_l + 0][o_l * 12 + rs]);
            v.y = f2bf(ls[i_l + 1][o_l * 12 + rs]);
            v.z = f2bf(ls[i_l + 2][o_l * 12 + rs]);
            v.w = f2bf(ls[i_l + 3][o_l * 12 + rs]);
            *(ushort4*)(W2f + ((size_t)(c * 12 + rs) * 16 + nt * 4 + kk) * 512
                            + lane * 8 + pos) = v;
        }
    } else if (blk == 632) {
        // ---------------- make_order ----------------
        int* cs = (int*)sm;
        if (tid < B_) cs[tid] = cam[tid];
        __syncthreads();
        if (tid < B_) {
            const int cb = cs[tid];
            int rank = 0;
            #pragma unroll 16
            for (int j = 0; j < B_; ++j) {
                int cj = cs[j];
                rank += (cj < cb || (cj == cb && j < tid)) ? 1 : 0;
            }
            ord[rank] = tid;
        }
    } else {
        // ---------------- repack_w1 ----------------
        float (*ls)[384] = (float(*)[384])sm;        // 32 x 384
        const int id = blk - 633;                    // 0..959
        const int f0 = (id & 15) * 32, i0 = ((id >> 4) & 3) * 32, c = id >> 6;
        #pragma unroll
        for (int it = 0; it < 12; ++it) {
            int idx = tid + it * 256;                // 3072 float4
            int fl = idx / 96, r = idx - fl * 96;
            float4 v = *(const float4*)(W1 + ((size_t)(c * F_ + f0 + fl)) * (H1_ * 12)
                                           + (size_t)i0 * 12 + r * 4);
            *(float4*)&ls[fl][r * 4] = v;
        }
        __syncthreads();
        const int i_l = tid >> 3, f_l = (tid & 7) * 4;
        const int i = i0 + i_l, f = f0 + f_l;
        const int kc = f >> 6, within = f & 63;
        const int cc = (within >> 3) ^ (i & 7), half = (within >> 2) & 1;
        #pragma unroll
        for (int pq = 0; pq < 12; ++pq) {
            ushort4 o;
            o.x = f2bf(ls[f_l + 0][i_l * 12 + pq]);
            o.y = f2bf(ls[f_l + 1][i_l * 12 + pq]);
            o.z = f2bf(ls[f_l + 2][i_l * 12 + pq]);
            o.w = f2bf(ls[f_l + 3][i_l * 12 + pq]);
            *(ushort4*)(W1s + (size_t)(c * 12 + pq) * 65536
                            + kc * 8192 + i * 64 + cc * 8 + half * 4) = o;
        }
    }
}

// ---------------------------------------------------------------------------
// Fused decoder (R18 best-measured config): BK=64, 2-buffer LDS staging via
// global_load_lds, counted vmcnt(6), raw barriers; phase2 swapped
// mfma(W2frag, h1frag) + cheap g-reduction; prefetches before h1s barrier.
// ---------------------------------------------------------------------------
__global__ __launch_bounds__(256) void fused_all(
    const unsigned short* __restrict__ xTs, const unsigned short* __restrict__ W1s,
    const unsigned short* __restrict__ W2f, const int* __restrict__ cam,
    const int* __restrict__ ord,
    const float* __restrict__ b1, const float* __restrict__ b2,
    const float* __restrict__ W3, const float* __restrict__ b3,
    float* __restrict__ out)
{
    __shared__ __align__(16) unsigned short smem[24576];   // 48 KB

    const int idx = blockIdx.x;
    const int swz = (idx & 7) * 192 + (idx >> 3);   // bijective XCD swizzle
    const int bpos = swz / 12, pq = swz - bpos * 12;
    const int b = ord[bpos];

    const int tid = threadIdx.x;
    const int w = tid >> 6, l = tid & 63;
    const int l15 = l & 15, g = l >> 4;
    const int c = cam[b];

    // ---------------- Phase 1: h1(64x128) = xT(64x512) * W1^T ----------------
    const unsigned short* xchunk = xTs + (size_t)b * 32768;             // 8 x 4096
    const unsigned short* wchunk = W1s + (size_t)(c * 12 + pq) * 65536; // 8 x 8192

    #define STAGE1(kc, buf)                                                       \
        {                                                                         \
            _Pragma("unroll")                                                     \
            for (int k = 0; k < 2; ++k)                                           \
                async_cp16(xchunk + (kc) * 4096 + (w * 2 + k) * 512 + l * 8,      \
                           smem + (buf) * 12288 + (w * 2 + k) * 512 + l * 8);     \
            _Pragma("unroll")                                                     \
            for (int k = 0; k < 4; ++k)                                           \
                async_cp16(wchunk + (kc) * 8192 + (w * 4 + k) * 512 + l * 8,      \
                           smem + (buf) * 12288 + 4096 + (w * 4 + k) * 512 + l * 8); \
        }

    f32x4 acc1[4][2];
    #pragma unroll
    for (int mt = 0; mt < 4; ++mt) {
        acc1[mt][0] = (f32x4){0.f, 0.f, 0.f, 0.f};
        acc1[mt][1] = (f32x4){0.f, 0.f, 0.f, 0.f};
    }

    STAGE1(0, 0);
    STAGE1(1, 1);

    const int sxor = (l15 & 7);
    #pragma unroll
    for (int kc = 0; kc < 8; ++kc) {
        if (kc < 7) { asm volatile("s_waitcnt vmcnt(6)" ::: "memory"); }
        else        { asm volatile("s_waitcnt vmcnt(0)" ::: "memory"); }
        __builtin_amdgcn_s_barrier();
        asm volatile("" ::: "memory");

        const int base = (kc & 1) * 12288;
        #pragma unroll
        for (int kk2 = 0; kk2 < 2; ++kk2) {
            const int cc = (kk2 * 4 + g) ^ sxor;
            short8_t af[4], bf[2];
            #pragma unroll
            for (int mt = 0; mt < 4; ++mt)
                af[mt] = *(const short8_t*)(smem + base + (16 * mt + l15) * 64 + cc * 8);
            #pragma unroll
            for (int ni = 0; ni < 2; ++ni)
                bf[ni] = *(const short8_t*)(smem + base + 4096
                                            + (32 * w + 16 * ni + l15) * 64 + cc * 8);
            #pragma unroll
            for (int mt = 0; mt < 4; ++mt)
                #pragma unroll
                for (int ni = 0; ni < 2; ++ni)
                    acc1[mt][ni] = __builtin_amdgcn_mfma_f32_16x16x32_bf16(
                        af[mt], bf[ni], acc1[mt][ni], 0, 0, 0);
        }

        asm volatile("" ::: "memory");
        __builtin_amdgcn_s_barrier();
        if (kc < 6) STAGE1(kc + 2, kc & 1);
    }
    #undef STAGE1

    // ---- phase-2 prefetches issued before the h1s barrier (T14) ----
    const unsigned short* W2base = W2f + (size_t)(c * 12 + w * 3) * 8192;
    short8_t bfr[2][4];
    #pragma unroll
    for (int kk = 0; kk < 4; ++kk)
        bfr[0][kk] = *(const short8_t*)(W2base + kk * 512 + l * 8);   // seg0: nt=0

    float w3v[4][4], b2v[4][4];
    #pragma unroll
    for (int nt = 0; nt < 4; ++nt)
        #pragma unroll
        for (int r = 0; r < 4; ++r) {
            w3v[nt][r] = W3[c * H2_ + nt * 16 + g * 4 + r];
            b2v[nt][r] = b2[c * H2_ + nt * 16 + g * 4 + r];
        }
    const float b3v = b3[c];
    const int p = pq >> 2, q = pq & 3;

    // bias + relu -> h1s [64][136] (bank-staggered)
    unsigned short* h1s = smem;
    #pragma unroll
    for (int ni = 0; ni < 2; ++ni) {
        const int i = 32 * w + 16 * ni + l15;
        const float b1v = b1[c * H1_ + i];
        #pragma unroll
        for (int mt = 0; mt < 4; ++mt)
            #pragma unroll
            for (int r = 0; r < 4; ++r) {
                float h = acc1[mt][ni][r] + b1v;
                h = h > 0.f ? h : 0.f;
                h1s[(16 * mt + 4 * g + r) * 136 + i] = f2bf(h);
            }
    }
    __syncthreads();

    // ---------------- Phase 2 (swapped operands) ----------------
    // a2 = h1 B-fragments: row t = 16mt + l15, k = i = 32kk + 8g .. +8
    short8_t a2[4][4];
    #pragma unroll
    for (int mt = 0; mt < 4; ++mt)
        #pragma unroll
        for (int kk = 0; kk < 4; ++kk)
            a2[mt][kk] = *(const short8_t*)&h1s[(16 * mt + l15) * 136 + 32 * kk + 8 * g];

    float s[4] = {0.f, 0.f, 0.f, 0.f};

    // seg = 0..11 : rs_local = seg>>2, nt = seg&3 ; 1-ahead 2-slot prefetch
    #pragma unroll
    for (int seg = 0; seg < 12; ++seg) {
        if (seg < 11) {
            const int ns = seg + 1;
            const unsigned short* nb = W2base + (ns >> 2) * 8192 + ((ns & 3) * 4) * 512;
            #pragma unroll
            for (int kk = 0; kk < 4; ++kk)
                bfr[(seg + 1) & 1][kk] = *(const short8_t*)(nb + kk * 512 + l * 8);
        }
        const int nt = seg & 3;
        #pragma unroll
        for (int mt = 0; mt < 4; ++mt) {
            f32x4 acc2 = (f32x4){0.f, 0.f, 0.f, 0.f};
            #pragma unroll
            for (int kk = 0; kk < 4; ++kk)
                acc2 = __builtin_amdgcn_mfma_f32_16x16x32_bf16(
                    bfr[seg & 1][kk], a2[mt][kk], acc2, 0, 0, 0);
            #pragma unroll
            for (int r = 0; r < 4; ++r)
                s[mt] = fmaf(w3v[nt][r], fmaxf(acc2[r] + b2v[nt][r], 0.f), s[mt]);
        }

        if (nt == 3) {
            const int rs = w * 3 + (seg >> 2);
            const int hrow = p * 3 + (rs >> 2), wcol = q * 4 + (rs & 3);
            #pragma unroll
            for (int mt = 0; mt < 4; ++mt) {
                s[mt] += __shfl_xor(s[mt], 16);
                s[mt] += __shfl_xor(s[mt], 32);
            }
            float v = (g & 1) ? ((g & 2) ? s[3] : s[1]) : ((g & 2) ? s[2] : s[0]);
            v += b3v;
            if (l < T_)
                out[(((size_t)b * T_ + l) * 9 + hrow) * 16 + wcol] =
                    1.f / (1.f + __expf(-v));
            s[0] = s[1] = s[2] = s[3] = 0.f;
        }
    }
}

// ---------------------------------------------------------------------------
// fp32 VALU fallback — used only if ws too small
// ---------------------------------------------------------------------------
__global__ __launch_bounds__(256) void fused_decoder_f32(
    const float* __restrict__ x,   const int* __restrict__ cam,
    const float* __restrict__ W1,  const float* __restrict__ b1,
    const float* __restrict__ W2,  const float* __restrict__ b2,
    const float* __restrict__ W3,  const float* __restrict__ b3,
    float* __restrict__ out)
{
    __shared__ float h1s[T_ * H1_];
    __shared__ float stage[8192];

    const int pq  = blockIdx.x;
    const int b   = blockIdx.y;
    const int p   = pq >> 2, q = pq & 3;
    const int tid = threadIdx.x;
    const int c   = cam[b];

    float* xs  = stage;
    float* w1s = stage + 2048;

    const int ig = tid & 31;
    const int tg = tid >> 5;

    float acc[8][4];
    #pragma unroll
    for (int a = 0; a < 8; ++a)
        #pragma unroll
        for (int j = 0; j < 4; ++j) acc[a][j] = 0.f;

    for (int f0 = 0; f0 < F_; f0 += 32) {
        __syncthreads();
        {
            int lane = tid & 63;
            int sub  = tid >> 6;
            if (lane < T_) {
                #pragma unroll
                for (int m = 0; m < 8; ++m) {
                    int kk = sub * 8 + m;
                    xs[kk * 64 + lane] = x[((size_t)b * F_ + f0 + kk) * T_ + lane];
                }
            }
        }
        for (int e = tid; e < 32 * H1_; e += 256) {
            int kk = e >> 7, i = e & 127;
            w1s[e] = W1[(((size_t)c * F_ + f0 + kk) * H1_ + i) * 12 + pq];
        }
        __syncthreads();
        #pragma unroll 8
        for (int kk = 0; kk < 32; ++kk) {
            float4 bv = *(const float4*)&w1s[kk * 128 + ig * 4];
            float4 a0 = *(const float4*)&xs[kk * 64 + tg * 8];
            float4 a1 = *(const float4*)&xs[kk * 64 + tg * 8 + 4];
            float at[8] = {a0.x, a0.y, a0.z, a0.w, a1.x, a1.y, a1.z, a1.w};
            #pragma unroll
            for (int tt = 0; tt < 8; ++tt) {
                acc[tt][0] = fmaf(at[tt], bv.x, acc[tt][0]);
                acc[tt][1] = fmaf(at[tt], bv.y, acc[tt][1]);
                acc[tt][2] = fmaf(at[tt], bv.z, acc[tt][2]);
                acc[tt][3] = fmaf(at[tt], bv.w, acc[tt][3]);
            }
        }
    }
    {
        float4 b1v = *(const float4*)&b1[c * H1_ + ig * 4];
        #pragma unroll
        for (int tt = 0; tt < 8; ++tt) {
            int t = tg * 8 + tt;
            if (t < T_) {
                float4 hv;
                hv.x = fmaxf(acc[tt][0] + b1v.x, 0.f);
                hv.y = fmaxf(acc[tt][1] + b1v.y, 0.f);
                hv.z = fmaxf(acc[tt][2] + b1v.z, 0.f);
                hv.w = fmaxf(acc[tt][3] + b1v.w, 0.f);
                *(float4*)&h1s[t * H1_ + ig * 4] = hv;
            }
        }
    }

    const int lane = tid & 63;
    const int wv   = tid >> 6;
    const float w3v = W3[c * H2_ + lane];
    const float b2v = b2[c * H2_ + lane];
    const float b3v = b3[c];
    float* w2s = stage;

    for (int rs = 0; rs < 12; ++rs) {
        __syncthreads();
        for (int e = tid; e < H1_ * H2_; e += 256) {
            int i = e >> 6, o = e & 63;
            w2s[e] = W2[(((size_t)c * H1_ + i) * H2_ + o) * 12 + rs];
        }
        __syncthreads();

        float acc2[15];
        #pragma unroll
        for (int j = 0; j < 15; ++j) acc2[j] = 0.f;

        for (int i = 0; i < H1_; i += 4) {
            float wa = w2s[(i + 0) * 64 + lane];
            float wb = w2s[(i + 1) * 64 + lane];
            float wc = w2s[(i + 2) * 64 + lane];
            float wd = w2s[(i + 3) * 64 + lane];
            #pragma unroll
            for (int j = 0; j < 15; ++j) {
                float4 h = *(const float4*)&h1s[(wv * 15 + j) * H1_ + i];
                acc2[j] = fmaf(h.x, wa, acc2[j]);
                acc2[j] = fmaf(h.y, wb, acc2[j]);
                acc2[j] = fmaf(h.z, wc, acc2[j]);
                acc2[j] = fmaf(h.w, wd, acc2[j]);
            }
        }

        const int r = rs >> 2, s = rs & 3;
        const int hrow = p * 3 + r, wcol = q * 4 + s;
        #pragma unroll
        for (int j = 0; j < 15; ++j) {
            float y = w3v * fmaxf(acc2[j] + b2v, 0.f);
            #pragma unroll
            for (int m = 32; m > 0; m >>= 1) y += __shfl_xor(y, m, 64);
            if (lane == j) {
                int t = wv * 15 + j;
                float v = y + b3v;
                out[(((size_t)b * T_ + t) * 9 + hrow) * 16 + wcol] = 1.f / (1.f + __expf(-v));
            }
        }
    }
}

// ---------------------------------------------------------------------------
extern "C" void kernel_launch(void* const* d_in, const int* in_sizes, int n_in,
                              void* d_out, int out_size, void* d_ws, size_t ws_size,
                              hipStream_t stream) {
    const float* x   = (const float*)d_in[0];
    const int*   cam = (const int*)  d_in[1];
    const float* W1  = (const float*)d_in[2];
    const float* b1  = (const float*)d_in[3];
    const float* W2  = (const float*)d_in[4];
    const float* b2  = (const float*)d_in[5];
    const float* W3  = (const float*)d_in[6];
    const float* b3  = (const float*)d_in[7];
    float* outp = (float*)d_out;

    const size_t n_xT  = (size_t)B_ * 32768;            //  4,194,304 (8 kc x 4096)
    const size_t n_w1s = (size_t)C_ * 12 * 65536;       // 11,796,480 (8 kc x 8192)
    const size_t n_w2f = (size_t)C_ * 12 * 16 * 512;    //  1,474,560 (fragment-major)
    const size_t needed = (n_xT + n_w1s + n_w2f) * sizeof(unsigned short)
                        + B_ * sizeof(int);

    if (d_ws != nullptr && ws_size >= needed) {
        unsigned short* xTs = (unsigned short*)d_ws;
        unsigned short* W1p = xTs + n_xT;
        unsigned short* W2p = W1p + n_w1s;
        int* ord = (int*)(W2p + n_w2f);
        prep_all<<<1593, 256, 0, stream>>>(x, W2, W1, cam, xTs, W2p, W1p, ord);
        fused_all<<<dim3(12 * B_), 256, 0, stream>>>(
            xTs, W1p, W2p, cam, ord, b1, b2, W3, b3, outp);
    } else {
        fused_decoder_f32<<<dim3(12, B_), 256, 0, stream>>>(
            x, cam, W1, b1, W2, b2, W3, b3, outp);
    }
}